// Round 1
// baseline (67.902 us; speedup 1.0000x reference)
//
#include <hip/hip_runtime.h>
#include <math.h>

#define KEPS 2.220446049250313e-13f   // 1000 * f64 eps, as in reference
#define LAMBDA 0.01f

// Per-sample geometry (fixed by the reference): K=6, H=16, W=16, P=5
#define NPIX 1536
#define NP 5

__global__ __launch_bounds__(256) void lm_mle_simflux_kernel(
    const float* __restrict__ smp,     // [B, 1536]
    const float* __restrict__ mu,      // [B, 1536]
    const float* __restrict__ dmu,     // [B, 1536, 5]
    const float* __restrict__ cur,     // [B, 5]
    const float* __restrict__ prmm,    // [5, 2]
    float* __restrict__ out,           // [B, 6]
    int B)
{
    const int lane = threadIdx.x & 63;
    const int wv   = threadIdx.x >> 6;
    const int b    = (blockIdx.x << 2) + wv;
    if (b >= B) return;

    const float* sb = smp + (size_t)b * NPIX;
    const float* mb = mu  + (size_t)b * NPIX;
    const float* jb = dmu + (size_t)b * NPIX * NP;

    float g0 = 0.f, g1 = 0.f, g2 = 0.f, g3 = 0.f, g4 = 0.f;
    float S[15];
    #pragma unroll
    for (int i = 0; i < 15; ++i) S[i] = 0.f;
    float logL = 0.f;

    // 1536 pixels / 64 lanes = 24 per lane, 4 pixels per iteration (float4 loads)
    for (int it = 0; it < 6; ++it) {
        const int pix0 = ((it << 6) + lane) << 2;     // 4*(it*64+lane)
        const float4 s4 = *reinterpret_cast<const float4*>(sb + pix0);
        const float4 m4 = *reinterpret_cast<const float4*>(mb + pix0);
        const float* jp = jb + (size_t)pix0 * NP;     // 20 floats for 4 pixels
        const float4 ja = *reinterpret_cast<const float4*>(jp + 0);
        const float4 jv1 = *reinterpret_cast<const float4*>(jp + 4);
        const float4 jc = *reinterpret_cast<const float4*>(jp + 8);
        const float4 jd = *reinterpret_cast<const float4*>(jp + 12);
        const float4 je = *reinterpret_cast<const float4*>(jp + 16);

        const float v[20] = {ja.x, ja.y, ja.z, ja.w,
                             jv1.x, jv1.y, jv1.z, jv1.w,
                             jc.x, jc.y, jc.z, jc.w,
                             jd.x, jd.y, jd.z, jd.w,
                             je.x, je.y, je.z, je.w};
        const float sm[4] = {s4.x, s4.y, s4.z, s4.w};
        const float mm[4] = {m4.x, m4.y, m4.z, m4.w};

        #pragma unroll
        for (int k = 0; k < 4; ++k) {
            const float m  = mm[k];
            const float mp = (m > 0.f) ? m : ((m < 0.f) ? KEPS : 0.f);
            const float s  = sm[k];
            const float r  = __builtin_amdgcn_rcpf(mp);
            const float w  = (s - mp) * r;
            const float dw = s * r * r;
            logL = fmaf(s, __logf(mp), logL) - mp;

            const float j0 = v[5*k+0], j1 = v[5*k+1], j2 = v[5*k+2],
                        j3 = v[5*k+3], j4 = v[5*k+4];
            g0 = fmaf(w, j0, g0);
            g1 = fmaf(w, j1, g1);
            g2 = fmaf(w, j2, g2);
            g3 = fmaf(w, j3, g3);
            g4 = fmaf(w, j4, g4);
            const float t0 = dw * j0, t1 = dw * j1, t2 = dw * j2,
                        t3 = dw * j3, t4 = dw * j4;
            // lower triangle (p,q), p>=q, row-major: idx = p(p+1)/2 + q
            S[0]  = fmaf(t0, j0, S[0]);
            S[1]  = fmaf(t1, j0, S[1]);
            S[2]  = fmaf(t1, j1, S[2]);
            S[3]  = fmaf(t2, j0, S[3]);
            S[4]  = fmaf(t2, j1, S[4]);
            S[5]  = fmaf(t2, j2, S[5]);
            S[6]  = fmaf(t3, j0, S[6]);
            S[7]  = fmaf(t3, j1, S[7]);
            S[8]  = fmaf(t3, j2, S[8]);
            S[9]  = fmaf(t3, j3, S[9]);
            S[10] = fmaf(t4, j0, S[10]);
            S[11] = fmaf(t4, j1, S[11]);
            S[12] = fmaf(t4, j2, S[12]);
            S[13] = fmaf(t4, j3, S[13]);
            S[14] = fmaf(t4, j4, S[14]);
        }
    }

    // wave-wide butterfly reduction (all lanes end with totals)
    #pragma unroll
    for (int off = 32; off > 0; off >>= 1) {
        logL += __shfl_xor(logL, off, 64);
        g0 += __shfl_xor(g0, off, 64);
        g1 += __shfl_xor(g1, off, 64);
        g2 += __shfl_xor(g2, off, 64);
        g3 += __shfl_xor(g3, off, 64);
        g4 += __shfl_xor(g4, off, 64);
        #pragma unroll
        for (int i = 0; i < 15; ++i) S[i] += __shfl_xor(S[i], off, 64);
    }

    // Build A = -(Hess + lambda*diag(Hess)*I) = S with diagonal scaled by (1+lambda)
    float A[5][5];
    A[0][0] = S[0] * (1.f + LAMBDA);
    A[1][0] = S[1];  A[0][1] = S[1];
    A[1][1] = S[2] * (1.f + LAMBDA);
    A[2][0] = S[3];  A[0][2] = S[3];
    A[2][1] = S[4];  A[1][2] = S[4];
    A[2][2] = S[5] * (1.f + LAMBDA);
    A[3][0] = S[6];  A[0][3] = S[6];
    A[3][1] = S[7];  A[1][3] = S[7];
    A[3][2] = S[8];  A[2][3] = S[8];
    A[3][3] = S[9] * (1.f + LAMBDA);
    A[4][0] = S[10]; A[0][4] = S[10];
    A[4][1] = S[11]; A[1][4] = S[11];
    A[4][2] = S[12]; A[2][4] = S[12];
    A[4][3] = S[13]; A[3][4] = S[13];
    A[4][4] = S[14] * (1.f + LAMBDA);

    float x[5] = {g0, g1, g2, g3, g4};

    // Gaussian elimination without pivoting (A is SPD here), fully static indices
    #pragma unroll
    for (int c = 0; c < 5; ++c) {
        const float inv = 1.0f / A[c][c];
        #pragma unroll
        for (int r2 = c + 1; r2 < 5; ++r2) {
            const float f = A[r2][c] * inv;
            #pragma unroll
            for (int q = c; q < 5; ++q) A[r2][q] = fmaf(-f, A[c][q], A[r2][q]);
            x[r2] = fmaf(-f, x[c], x[r2]);
        }
    }
    #pragma unroll
    for (int r2 = 4; r2 >= 0; --r2) {
        float acc = x[r2];
        #pragma unroll
        for (int q = r2 + 1; q < 5; ++q) acc = fmaf(-A[r2][q], x[q], acc);
        x[r2] = acc / A[r2][r2];
    }

    if (lane == 0) {
        float* ob = out + (size_t)b * 6;
        #pragma unroll
        for (int p = 0; p < 5; ++p) {
            float dt = x[p];
            const float c = cur[(size_t)b * NP + p];
            if (dt != dt) dt = -0.1f * c;       // NaN fallback
            float nc = c + dt;
            const float lo = prmm[2 * p];
            const float hi = prmm[2 * p + 1];
            nc = fminf(fmaxf(nc, lo), hi);
            ob[p] = nc;
        }
        ob[5] = logL;
    }
}

extern "C" void kernel_launch(void* const* d_in, const int* in_sizes, int n_in,
                              void* d_out, int out_size, void* d_ws, size_t ws_size,
                              hipStream_t stream) {
    const float* smp  = (const float*)d_in[0];
    const float* mu   = (const float*)d_in[1];
    const float* dmu  = (const float*)d_in[2];
    const float* cur  = (const float*)d_in[3];
    const float* prmm = (const float*)d_in[4];
    float* out = (float*)d_out;

    const int B = in_sizes[3] / NP;           // cur is [B,5]
    const int blocks = (B + 3) / 4;           // 4 waves (samples) per 256-thread block
    lm_mle_simflux_kernel<<<blocks, 256, 0, stream>>>(smp, mu, dmu, cur, prmm, out, B);
}